// Round 4
// baseline (270.341 us; speedup 1.0000x reference)
//
#include <hip/hip_runtime.h>

typedef __bf16 bf16x8 __attribute__((ext_vector_type(8)));
typedef __bf16 bf16x4 __attribute__((ext_vector_type(4)));
typedef float f32x4 __attribute__((ext_vector_type(4)));

#define D_MODEL 1024
#define NUM_HEADS 16
#define DK 64
#define BATCH 2
#define SEQ 2048
#define M_ROWS (BATCH*SEQ)

// (1/sqrt(DK)) * log2(e): folded into Q projection so attn uses exp2(z) raw
#define QSCALE 0.18033688011112042f

#define GLOAD_LDS16(gp, lp) __builtin_amdgcn_global_load_lds( \
    (__attribute__((address_space(1))) void*)(gp), \
    (__attribute__((address_space(3))) void*)(lp), 16, 0, 0)

#define ACT ((size_t)M_ROWS * D_MODEL)   // 4194304 = 2^22
#define WSZ ((size_t)D_MODEL * D_MODEL)  // 1048576 = 2^20

// One fused fp32->bf16 pass over all 7 tensors (dsts contiguous in ws):
// linear elem e in [0, 3*ACT + 4*WSZ = 2^24); region decode is shift/mask.
__global__ __launch_bounds__(256) void cvt_all(
    const float* __restrict__ q, const float* __restrict__ k,
    const float* __restrict__ v, const float* __restrict__ wq,
    const float* __restrict__ wk, const float* __restrict__ wv,
    const float* __restrict__ wo, __bf16* __restrict__ dst)
{
  size_t e = ((size_t)blockIdx.x * 256 + threadIdx.x) * 8;
  const float* s;
  size_t off;
  if (e < 3 * ACT) {
    int t = (int)(e >> 22);
    s = t == 0 ? q : (t == 1 ? k : v);
    off = e & (ACT - 1);
  } else {
    size_t e2 = e - 3 * ACT;
    int t = (int)(e2 >> 20);
    s = t == 0 ? wq : (t == 1 ? wk : (t == 2 ? wv : wo));
    off = e2 & (WSZ - 1);
  }
  float4 a = *(const float4*)(s + off);
  float4 b = *(const float4*)(s + off + 4);
  bf16x8 o;
  o[0] = (__bf16)a.x; o[1] = (__bf16)a.y; o[2] = (__bf16)a.z; o[3] = (__bf16)a.w;
  o[4] = (__bf16)b.x; o[5] = (__bf16)b.y; o[6] = (__bf16)b.z; o[7] = (__bf16)b.w;
  *(bf16x8*)(dst + e) = o;
}

// 128x128 GEMM tile, BK=64, XOR-swizzled LDS: row r's chunk j stored at
// chunk pos j^(r&7). Read bank base = 4*((J)^(l16&7)) -> uniform over 32
// banks (8 lanes/4-bank group = b128 inherent rate, no excess conflict).
template <typename OutT>
__device__ __forceinline__ void gemm_body(
    const __bf16* __restrict__ A, const __bf16* __restrict__ W,
    const float* __restrict__ bias, OutT* __restrict__ C,
    int M, int N, int K, int m0, int n0, float scale)
{
  __shared__ __align__(16) __bf16 sA[128*64];
  __shared__ __align__(16) __bf16 sB[128*64];
  const int tid  = threadIdx.x;
  const int wave = tid >> 6;
  const int lane = tid & 63;
  const int l16  = lane & 15;
  const int quad = lane >> 4;
  const int wm = (wave >> 1) * 64;
  const int wn = (wave & 1) * 64;

  f32x4 acc[4][4] = {};

  // staging: thread's lds slot c=i*256+tid holds row c>>3, chunk pos c&7;
  // source global chunk = (c&7)^((c>>3)&7) = (tid&7)^((tid>>3)&7) (i-invariant)
  const int gsw = (((tid & 7) ^ ((tid >> 3) & 7))) * 8;
  long aoff[4], boff[4];
#pragma unroll
  for (int i = 0; i < 4; i++) {
    int row = (i * 256 + tid) >> 3;
    aoff[i] = (long)(m0 + row) * K + gsw;
    boff[i] = (long)(n0 + row) * K + gsw;
  }
  const int rsw = l16 & 7;  // read swizzle selector (= row&7 for all frags)

  for (int k0 = 0; k0 < K; k0 += 64) {
    __syncthreads();
#pragma unroll
    for (int i = 0; i < 4; i++) {
      GLOAD_LDS16(A + aoff[i] + k0, (char*)sA + i * 4096 + wave * 1024);
      GLOAD_LDS16(W + boff[i] + k0, (char*)sB + i * 4096 + wave * 1024);
    }
    __syncthreads();
#pragma unroll
    for (int ks = 0; ks < 2; ks++) {
      bf16x8 af[4], bf[4];
#pragma unroll
      for (int i = 0; i < 4; i++)
        af[i] = *(const bf16x8*)&sA[(wm + i * 16 + l16) * 64 + ((ks * 4 + quad) ^ rsw) * 8];
#pragma unroll
      for (int j = 0; j < 4; j++)
        bf[j] = *(const bf16x8*)&sB[(wn + j * 16 + l16) * 64 + ((ks * 4 + quad) ^ rsw) * 8];
#pragma unroll
      for (int i = 0; i < 4; i++)
#pragma unroll
        for (int j = 0; j < 4; j++)
          acc[i][j] = __builtin_amdgcn_mfma_f32_16x16x32_bf16(af[i], bf[j], acc[i][j], 0, 0, 0);
    }
  }

#pragma unroll
  for (int j = 0; j < 4; j++) {
    int col = n0 + wn + j * 16 + l16;
    float bv = bias[col];
#pragma unroll
    for (int i = 0; i < 4; i++) {
      long row0 = m0 + wm + i * 16 + quad * 4;
#pragma unroll
      for (int r = 0; r < 4; r++)
        C[(row0 + r) * N + col] = (OutT)((acc[i][j][r] + bv) * scale);
    }
  }
}

__global__ __launch_bounds__(256) void gemm_qkv(
    const __bf16* __restrict__ Abase, const __bf16* __restrict__ Wbase,
    const float* __restrict__ b0, const float* __restrict__ b1,
    const float* __restrict__ b2, __bf16* __restrict__ Cbase)
{
  int z = blockIdx.z;
  const __bf16* A = Abase + (size_t)z * M_ROWS * D_MODEL;
  const __bf16* W = Wbase + (size_t)z * D_MODEL * D_MODEL;
  const float* bias = z == 0 ? b0 : (z == 1 ? b1 : b2);
  float scale = z == 0 ? QSCALE : 1.0f;  // fold softmax scale into Q
  __bf16* C = Cbase + (size_t)z * M_ROWS * D_MODEL;
  gemm_body<__bf16>(A, W, bias, C, M_ROWS, D_MODEL, D_MODEL,
                    blockIdx.y * 128, blockIdx.x * 128, scale);
}

__global__ __launch_bounds__(256) void gemm_out(
    const __bf16* __restrict__ A, const __bf16* __restrict__ W,
    const float* __restrict__ bias, float* __restrict__ C)
{
  gemm_body<float>(A, W, bias, C, M_ROWS, D_MODEL, D_MODEL,
                   blockIdx.y * 128, blockIdx.x * 128, 1.0f);
}

// Flash attention, no-max softmax; scale pre-folded into Q so P = exp2(S^T).
// Block = 128 q-rows of one (b,h), 4 waves x 32 q-rows each, 256 threads.
// Register blocking: each wave owns two 16-q groups (g=0,1); every sK K-frag
// and sVt V-frag read is reused by both groups -> per-output LDS reads halve
// vs the 8-wave/16-q version (R3: VALU 48%, Mfma 19%, 33% stall).
//
// Key-axis permutation trick (pi): S^T outputs for nt=2kt,2kt+1 ARE the PV
// A-fragment; V staged at pi-permuted columns. P never touches LDS.
__global__ __launch_bounds__(256) void attn_kernel(
    const __bf16* __restrict__ Q, const __bf16* __restrict__ K,
    const __bf16* __restrict__ V, __bf16* __restrict__ O)
{
  constexpr int SV_LD = 136;  // 128 keys + pad

  __shared__ __align__(16) __bf16 sK[128 * 64];       // swizzled [key][d]
  __shared__ __align__(16) __bf16 sVt[DK * SV_LD];    // [d][pi(key)]

  const int tid  = threadIdx.x;
  const int wave = tid >> 6;
  const int lane = tid & 63;
  const int l16  = lane & 15;
  const int quad = lane >> 4;

  const int bh = blockIdx.y;
  const int b  = bh >> 4, h = bh & (NUM_HEADS - 1);
  const int q0 = blockIdx.x * 128;
  const long base = (long)b * SEQ * D_MODEL + h * DK;

  // Q fragments (B operand of S^T MFMA), register-resident for the kernel.
  // Wave owns q-rows [wave*32, wave*32+32); group g covers +g*16.
  bf16x8 aq[2][2];
#pragma unroll
  for (int g = 0; g < 2; g++) {
    const __bf16* qrow =
        Q + base + (long)(q0 + wave * 32 + g * 16 + l16) * D_MODEL + quad * 8;
    aq[g][0] = *(const bf16x8*)(qrow);
    aq[g][1] = *(const bf16x8*)(qrow + 32);
  }

  // K reg-staging, swizzled: slot c=i*256+tid -> row c>>3, chunk pos c&7;
  // source chunk = (tid&7)^((tid>>3)&7)  (i-invariant since 256|8 rows)
  const int gsw = (((tid & 7) ^ ((tid >> 3) & 7))) * 8;
  const __bf16* kp[4];
#pragma unroll
  for (int i = 0; i < 4; i++)
    kp[i] = K + base + (long)((i * 256 + tid) >> 3) * D_MODEL + gsw;
  const int rsw = l16 & 7;

  // V staging: lane owns key-pair (2*lane, 2*lane+1); wave owns d-group
  // [wave*16, wave*16+16). Destination column pi-permuted; pairs adjacent.
  const __bf16* vp0 = V + base + (long)(2 * lane) * D_MODEL + wave * 16;
  const int k5 = (2 * lane) & 31;
  const int pos5 = ((k5 & 12) << 1) | ((k5 & 16) >> 2) | (k5 & 3);
  const int vcol = (lane >> 4) * 16 + (pos5 >> 1);  // packed-u32 column

  // prologue prefetch: tile 0
  uint4 kr[4], vr[4];
#pragma unroll
  for (int i = 0; i < 4; i++) kr[i] = *(const uint4*)(kp[i]);
  vr[0] = *(const uint4*)(vp0);
  vr[1] = *(const uint4*)(vp0 + 8);
  vr[2] = *(const uint4*)(vp0 + D_MODEL);
  vr[3] = *(const uint4*)(vp0 + D_MODEL + 8);

  f32x4 lacc[2] = {};
  f32x4 o[2][4] = {};  // o[g][dt] reg r -> out[q=g*16+quad*4+r][d=dt*16+l16]

  for (int t = 0; t < SEQ / 128; t++) {
    __syncthreads();  // previous tile's LDS reads done
    // write staged K (byte offset (i*256+tid)*16)
#pragma unroll
    for (int i = 0; i < 4; i++)
      *(uint4*)((char*)sK + i * 4096 + tid * 16) = kr[i];
    // write staged V transposed + pi-permuted, pair-packed b32 (2-way = free)
    {
      const ushort* e0 = (const ushort*)&vr[0];  // key 2l, d wave*16+0..7
      const ushort* e1 = (const ushort*)&vr[1];  // key 2l, d wave*16+8..15
      const ushort* e2 = (const ushort*)&vr[2];  // key 2l+1, d +0..7
      const ushort* e3 = (const ushort*)&vr[3];  // key 2l+1, d +8..15
      uint* dst = (uint*)sVt;
#pragma unroll
      for (int j = 0; j < 8; j++) {
        dst[(wave * 16 + j) * (SV_LD / 2) + vcol] =
            (uint)e0[j] | ((uint)e2[j] << 16);
        dst[(wave * 16 + 8 + j) * (SV_LD / 2) + vcol] =
            (uint)e1[j] | ((uint)e3[j] << 16);
      }
    }
    // prefetch tile t+1 into registers: latency hides under barrier + compute
    if (t + 1 < SEQ / 128) {
      long adv = (long)(t + 1) * 128 * D_MODEL;
#pragma unroll
      for (int i = 0; i < 4; i++) kr[i] = *(const uint4*)(kp[i] + adv);
      vr[0] = *(const uint4*)(vp0 + adv);
      vr[1] = *(const uint4*)(vp0 + adv + 8);
      vr[2] = *(const uint4*)(vp0 + adv + D_MODEL);
      vr[3] = *(const uint4*)(vp0 + adv + D_MODEL + 8);
    }
    __syncthreads();

    // Per 32-key block kt: S^T = K Q^T for nt=2kt,2kt+1 (K-frags shared by
    // both q-groups), softmax in-reg, then 4 PV MFMAs per group (V-frags
    // shared by both groups).
#pragma unroll
    for (int kt = 0; kt < 4; kt++) {
      bf16x8 af0, af1;
#pragma unroll
      for (int hh = 0; hh < 2; hh++) {
        int nt = 2 * kt + hh;
        bf16x8 b0 = *(const bf16x8*)&sK[(nt * 16 + l16) * 64 + (quad ^ rsw) * 8];
        bf16x8 b1 = *(const bf16x8*)&sK[(nt * 16 + l16) * 64 + ((4 + quad) ^ rsw) * 8];
        f32x4 z0 = {}, z1 = {};
        __builtin_amdgcn_s_setprio(1);
        z0 = __builtin_amdgcn_mfma_f32_16x16x32_bf16(b0, aq[0][0], z0, 0, 0, 0);
        z0 = __builtin_amdgcn_mfma_f32_16x16x32_bf16(b1, aq[0][1], z0, 0, 0, 0);
        z1 = __builtin_amdgcn_mfma_f32_16x16x32_bf16(b0, aq[1][0], z1, 0, 0, 0);
        z1 = __builtin_amdgcn_mfma_f32_16x16x32_bf16(b1, aq[1][1], z1, 0, 0, 0);
        __builtin_amdgcn_s_setprio(0);
        f32x4 p0, p1;
#pragma unroll
        for (int r = 0; r < 4; r++) p0[r] = exp2f(z0[r]);
#pragma unroll
        for (int r = 0; r < 4; r++) p1[r] = exp2f(z1[r]);
        lacc[0] += p0;
        lacc[1] += p1;
#pragma unroll
        for (int r = 0; r < 4; r++) af0[hh * 4 + r] = (__bf16)p0[r];
#pragma unroll
        for (int r = 0; r < 4; r++) af1[hh * 4 + r] = (__bf16)p1[r];
      }
      // O += P @ V : A = af (in-register, pi layout), B = V[pi(key)][d]
      __builtin_amdgcn_s_setprio(1);
#pragma unroll
      for (int dt = 0; dt < 4; dt++) {
        bf16x8 bv = *(const bf16x8*)&sVt[(dt * 16 + l16) * SV_LD + kt * 32 + quad * 8];
        o[0][dt] = __builtin_amdgcn_mfma_f32_16x16x32_bf16(af0, bv, o[0][dt], 0, 0, 0);
        o[1][dt] = __builtin_amdgcn_mfma_f32_16x16x32_bf16(af1, bv, o[1][dt], 0, 0, 0);
      }
      __builtin_amdgcn_s_setprio(0);
    }
  }

  // per-group lsum for q=l16: horizontal + cross-quad reduce, then store
#pragma unroll
  for (int g = 0; g < 2; g++) {
    float ls = lacc[g][0] + lacc[g][1] + lacc[g][2] + lacc[g][3];
    ls += __shfl_xor(ls, 16, 64);
    ls += __shfl_xor(ls, 32, 64);
    float rls[4];
#pragma unroll
    for (int r = 0; r < 4; r++)
      rls[r] = 1.0f / __shfl(ls, quad * 4 + r, 64);  // lane q holds lsum[q]
#pragma unroll
    for (int dt = 0; dt < 4; dt++) {
#pragma unroll
      for (int r = 0; r < 4; r++) {
        int s = q0 + wave * 32 + g * 16 + quad * 4 + r;
        int d = dt * 16 + l16;
        O[base + (long)s * D_MODEL + d] = (__bf16)(o[g][dt][r] * rls[r]);
      }
    }
  }
}

extern "C" void kernel_launch(void* const* d_in, const int* in_sizes, int n_in,
                              void* d_out, int out_size, void* d_ws, size_t ws_size,
                              hipStream_t stream) {
  const float* q  = (const float*)d_in[0];
  const float* k  = (const float*)d_in[1];
  const float* v  = (const float*)d_in[2];
  const float* Wq = (const float*)d_in[3];
  const float* bq = (const float*)d_in[4];
  const float* Wk = (const float*)d_in[5];
  const float* bk = (const float*)d_in[6];
  const float* Wv = (const float*)d_in[7];
  const float* bv = (const float*)d_in[8];
  const float* Wo = (const float*)d_in[9];
  const float* bo = (const float*)d_in[10];
  float* out = (float*)d_out;

  __bf16* qc  = (__bf16*)d_ws;          // qc,kc,vc contiguous
  __bf16* Wqc = qc + 3 * ACT;           // Wq,Wk,Wv,Wo contiguous
  __bf16* wsQ = Wqc + 4 * WSZ;          // Q,K,V projections contiguous
  __bf16* wsAo = qc;                    // attn out reuses qc

  dim3 blk(256);
  // one fused cvt pass: 3*ACT + 4*WSZ = 2^24 elems, 8/thread
  cvt_all<<<dim3((3 * ACT + 4 * WSZ) / 2048), blk, 0, stream>>>(
      q, k, v, Wq, Wk, Wv, Wo, qc);

  gemm_qkv<<<dim3(D_MODEL / 128, M_ROWS / 128, 3), blk, 0, stream>>>(
      qc, Wqc, bq, bk, bv, wsQ);

  attn_kernel<<<dim3(SEQ / 128, BATCH * NUM_HEADS), dim3(256), 0, stream>>>(
      wsQ, wsQ + ACT, wsQ + 2 * ACT, wsAo);

  gemm_out<<<dim3(D_MODEL / 128, M_ROWS / 128), blk, 0, stream>>>(
      wsAo, Wqc + 3 * WSZ, bo, out);
}

// Round 5
// 246.746 us; speedup vs baseline: 1.0956x; 1.0956x over previous
//
#include <hip/hip_runtime.h>

typedef __bf16 bf16x8 __attribute__((ext_vector_type(8)));
typedef __bf16 bf16x4 __attribute__((ext_vector_type(4)));
typedef float f32x4 __attribute__((ext_vector_type(4)));

#define D_MODEL 1024
#define NUM_HEADS 16
#define DK 64
#define BATCH 2
#define SEQ 2048
#define M_ROWS (BATCH*SEQ)

// (1/sqrt(DK)) * log2(e): folded into Q projection so attn uses exp2(z) raw
#define QSCALE 0.18033688011112042f

#if defined(__has_builtin)
#if __has_builtin(__builtin_amdgcn_exp2f)
#define EXP2(x) __builtin_amdgcn_exp2f(x)
#endif
#endif
#ifndef EXP2
#define EXP2(x) exp2f(x)
#endif

#define GLOAD_LDS16(gp, lp) __builtin_amdgcn_global_load_lds( \
    (__attribute__((address_space(1))) void*)(gp), \
    (__attribute__((address_space(3))) void*)(lp), 16, 0, 0)

#define ACT ((size_t)M_ROWS * D_MODEL)   // 4194304 = 2^22
#define WSZ ((size_t)D_MODEL * D_MODEL)  // 1048576 = 2^20

// One fused fp32->bf16 pass over all 7 tensors (dsts contiguous in ws):
// linear elem e in [0, 3*ACT + 4*WSZ = 2^24); region decode is shift/mask.
__global__ __launch_bounds__(256) void cvt_all(
    const float* __restrict__ q, const float* __restrict__ k,
    const float* __restrict__ v, const float* __restrict__ wq,
    const float* __restrict__ wk, const float* __restrict__ wv,
    const float* __restrict__ wo, __bf16* __restrict__ dst)
{
  size_t e = ((size_t)blockIdx.x * 256 + threadIdx.x) * 8;
  const float* s;
  size_t off;
  if (e < 3 * ACT) {
    int t = (int)(e >> 22);
    s = t == 0 ? q : (t == 1 ? k : v);
    off = e & (ACT - 1);
  } else {
    size_t e2 = e - 3 * ACT;
    int t = (int)(e2 >> 20);
    s = t == 0 ? wq : (t == 1 ? wk : (t == 2 ? wv : wo));
    off = e2 & (WSZ - 1);
  }
  float4 a = *(const float4*)(s + off);
  float4 b = *(const float4*)(s + off + 4);
  bf16x8 o;
  o[0] = (__bf16)a.x; o[1] = (__bf16)a.y; o[2] = (__bf16)a.z; o[3] = (__bf16)a.w;
  o[4] = (__bf16)b.x; o[5] = (__bf16)b.y; o[6] = (__bf16)b.z; o[7] = (__bf16)b.w;
  *(bf16x8*)(dst + e) = o;
}

// 128x128 GEMM tile, BK=64, XOR-swizzled LDS: row r's chunk j stored at
// chunk pos j^(r&7). Read bank base = 4*((J)^(l16&7)) -> uniform over 32
// banks (8 lanes/4-bank group = b128 inherent rate, no excess conflict).
template <typename OutT>
__device__ __forceinline__ void gemm_body(
    const __bf16* __restrict__ A, const __bf16* __restrict__ W,
    const float* __restrict__ bias, OutT* __restrict__ C,
    int M, int N, int K, int m0, int n0, float scale)
{
  __shared__ __align__(16) __bf16 sA[128*64];
  __shared__ __align__(16) __bf16 sB[128*64];
  const int tid  = threadIdx.x;
  const int wave = tid >> 6;
  const int lane = tid & 63;
  const int l16  = lane & 15;
  const int quad = lane >> 4;
  const int wm = (wave >> 1) * 64;
  const int wn = (wave & 1) * 64;

  f32x4 acc[4][4] = {};

  // staging: thread's lds slot c=i*256+tid holds row c>>3, chunk pos c&7;
  // source global chunk = (c&7)^((c>>3)&7) = (tid&7)^((tid>>3)&7) (i-invariant)
  const int gsw = (((tid & 7) ^ ((tid >> 3) & 7))) * 8;
  long aoff[4], boff[4];
#pragma unroll
  for (int i = 0; i < 4; i++) {
    int row = (i * 256 + tid) >> 3;
    aoff[i] = (long)(m0 + row) * K + gsw;
    boff[i] = (long)(n0 + row) * K + gsw;
  }
  const int rsw = l16 & 7;  // read swizzle selector (= row&7 for all frags)

  for (int k0 = 0; k0 < K; k0 += 64) {
    __syncthreads();
#pragma unroll
    for (int i = 0; i < 4; i++) {
      GLOAD_LDS16(A + aoff[i] + k0, (char*)sA + i * 4096 + wave * 1024);
      GLOAD_LDS16(W + boff[i] + k0, (char*)sB + i * 4096 + wave * 1024);
    }
    __syncthreads();
#pragma unroll
    for (int ks = 0; ks < 2; ks++) {
      bf16x8 af[4], bf[4];
#pragma unroll
      for (int i = 0; i < 4; i++)
        af[i] = *(const bf16x8*)&sA[(wm + i * 16 + l16) * 64 + ((ks * 4 + quad) ^ rsw) * 8];
#pragma unroll
      for (int j = 0; j < 4; j++)
        bf[j] = *(const bf16x8*)&sB[(wn + j * 16 + l16) * 64 + ((ks * 4 + quad) ^ rsw) * 8];
#pragma unroll
      for (int i = 0; i < 4; i++)
#pragma unroll
        for (int j = 0; j < 4; j++)
          acc[i][j] = __builtin_amdgcn_mfma_f32_16x16x32_bf16(af[i], bf[j], acc[i][j], 0, 0, 0);
    }
  }

#pragma unroll
  for (int j = 0; j < 4; j++) {
    int col = n0 + wn + j * 16 + l16;
    float bv = bias[col];
#pragma unroll
    for (int i = 0; i < 4; i++) {
      long row0 = m0 + wm + i * 16 + quad * 4;
#pragma unroll
      for (int r = 0; r < 4; r++)
        C[(row0 + r) * N + col] = (OutT)((acc[i][j][r] + bv) * scale);
    }
  }
}

__global__ __launch_bounds__(256) void gemm_qkv(
    const __bf16* __restrict__ Abase, const __bf16* __restrict__ Wbase,
    const float* __restrict__ b0, const float* __restrict__ b1,
    const float* __restrict__ b2, __bf16* __restrict__ Cbase)
{
  int z = blockIdx.z;
  const __bf16* A = Abase + (size_t)z * M_ROWS * D_MODEL;
  const __bf16* W = Wbase + (size_t)z * D_MODEL * D_MODEL;
  const float* bias = z == 0 ? b0 : (z == 1 ? b1 : b2);
  float scale = z == 0 ? QSCALE : 1.0f;  // fold softmax scale into Q
  __bf16* C = Cbase + (size_t)z * M_ROWS * D_MODEL;
  gemm_body<__bf16>(A, W, bias, C, M_ROWS, D_MODEL, D_MODEL,
                    blockIdx.y * 128, blockIdx.x * 128, scale);
}

__global__ __launch_bounds__(256) void gemm_out(
    const __bf16* __restrict__ A, const __bf16* __restrict__ W,
    const float* __restrict__ bias, float* __restrict__ C)
{
  gemm_body<float>(A, W, bias, C, M_ROWS, D_MODEL, D_MODEL,
                   blockIdx.y * 128, blockIdx.x * 128, 1.0f);
}

// Flash attention, no-max softmax; scale pre-folded into Q so P = exp2(S^T).
// Block = 64 q-rows of one (b,h), 8 waves, 512 threads.
// Wave (g = w&3, kh = w>>2): q-group g (16 rows) x key-half kh (64 of the
// 128 keys per tile). Per-wave registers identical to the R3 shape (VGPR 48,
// no spill); per-wave work halves; grid = 1024 blocks = 4 blocks/CU x 8
// waves = 32 waves/CU (vs 16), 4 independent barrier domains per CU.
// Key-half partials (o, lsum) are combined through LDS in the epilogue
// (o-scratch reuses sK; runs once).
//
// Key-axis permutation trick (pi): S^T outputs for the two nt of a 32-key
// block ARE the PV A-fragment; V staged at pi-permuted columns. P never
// touches LDS.
__global__ __launch_bounds__(512) void attn_kernel(
    const __bf16* __restrict__ Q, const __bf16* __restrict__ K,
    const __bf16* __restrict__ V, __bf16* __restrict__ O)
{
  constexpr int SV_LD = 136;  // 128 keys + pad

  __shared__ __align__(16) __bf16 sK[128 * 64];       // swizzled [key][d]; f32x4 scratch in epilogue
  __shared__ __align__(16) __bf16 sVt[DK * SV_LD];    // [d][pi(key)]
  __shared__ float lsbuf[8][16];

  const int tid  = threadIdx.x;
  const int wave = tid >> 6;
  const int g    = wave & 3;   // q-group (16 rows)
  const int kh   = wave >> 2;  // key half (64 keys)
  const int lane = tid & 63;
  const int l16  = lane & 15;
  const int quad = lane >> 4;

  const int bh = blockIdx.y;
  const int b  = bh >> 4, h = bh & (NUM_HEADS - 1);
  const int q0 = blockIdx.x * 64;
  const long base = (long)b * SEQ * D_MODEL + h * DK;

  // Q fragments (B operand of S^T MFMA), register-resident for the kernel
  const __bf16* qrow = Q + base + (long)(q0 + g * 16 + l16) * D_MODEL + quad * 8;
  const bf16x8 aq0 = *(const bf16x8*)(qrow);
  const bf16x8 aq1 = *(const bf16x8*)(qrow + 32);

  // K reg-staging, swizzled: slot c=i*512+tid -> row c>>3, chunk pos c&7;
  // source chunk = (tid&7)^((tid>>3)&7) (i-invariant)
  const int gsw = (((tid & 7) ^ ((tid >> 3) & 7))) * 8;
  const __bf16* kp[2];
#pragma unroll
  for (int i = 0; i < 2; i++)
    kp[i] = K + base + (long)((i * 512 + tid) >> 3) * D_MODEL + gsw;
  const int rsw = l16 & 7;

  // V staging: lane owns physical key-pair (2*lane, 2*lane+1), wave owns
  // d-group wave*8. Destination column is pi-permuted: pos bits
  // [4:3]=key[3:2], [2]=key[4], [1:0]=key[1:0]; pairs stay adjacent.
  const __bf16* vp0 = V + base + (long)(2 * lane) * D_MODEL + wave * 8;
  const int k5 = (2 * lane) & 31;
  const int pos5 = ((k5 & 12) << 1) | ((k5 & 16) >> 2) | (k5 & 3);
  const int vcol = (lane >> 4) * 16 + (pos5 >> 1);  // packed-u32 column

  // prologue prefetch: tile 0
  uint4 kr0 = *(const uint4*)(kp[0]);
  uint4 kr1 = *(const uint4*)(kp[1]);
  uint4 vr0 = *(const uint4*)(vp0);
  uint4 vr1 = *(const uint4*)(vp0 + D_MODEL);

  f32x4 lacc = {};
  f32x4 o[4] = {};  // o[dt] reg r -> partial out[q=g*16+quad*4+r][d=dt*16+l16]

  for (int t = 0; t < SEQ / 128; t++) {
    __syncthreads();  // previous tile's LDS reads done
    // write staged K (byte offset (i*512+tid)*16)
    *(uint4*)((char*)sK + tid * 16) = kr0;
    *(uint4*)((char*)sK + 8192 + tid * 16) = kr1;
    // write staged V transposed + pi-permuted, pair-packed b32 (2-way = free)
    {
      const ushort* e0 = (const ushort*)&vr0;
      const ushort* e1 = (const ushort*)&vr1;
      uint* dst = (uint*)sVt;
#pragma unroll
      for (int j = 0; j < 8; j++)
        dst[(wave * 8 + j) * (SV_LD / 2) + vcol] = (uint)e0[j] | ((uint)e1[j] << 16);
    }
    // prefetch tile t+1 into registers: latency hides under barrier + compute
    if (t + 1 < SEQ / 128) {
      long adv = (long)(t + 1) * 128 * D_MODEL;
      kr0 = *(const uint4*)(kp[0] + adv);
      kr1 = *(const uint4*)(kp[1] + adv);
      vr0 = *(const uint4*)(vp0 + adv);
      vr1 = *(const uint4*)(vp0 + adv + D_MODEL);
    }
    __syncthreads();

    // Wave's half: 32-key blocks kt = kh*2 + kl. S^T for the two 16-key
    // rows of each block, softmax in-reg, af assembled (pi layout), 4 PV.
#pragma unroll
    for (int kl = 0; kl < 2; kl++) {
      const int kt = kh * 2 + kl;
      bf16x8 af;
#pragma unroll
      for (int hh = 0; hh < 2; hh++) {
        int nt = kt * 2 + hh;  // = kh*4 + kl*2 + hh
        bf16x8 b0 = *(const bf16x8*)&sK[(nt * 16 + l16) * 64 + (quad ^ rsw) * 8];
        bf16x8 b1 = *(const bf16x8*)&sK[(nt * 16 + l16) * 64 + ((4 + quad) ^ rsw) * 8];
        f32x4 z = {};
        __builtin_amdgcn_s_setprio(1);
        z = __builtin_amdgcn_mfma_f32_16x16x32_bf16(b0, aq0, z, 0, 0, 0);
        z = __builtin_amdgcn_mfma_f32_16x16x32_bf16(b1, aq1, z, 0, 0, 0);
        __builtin_amdgcn_s_setprio(0);
        f32x4 p;
#pragma unroll
        for (int r = 0; r < 4; r++) p[r] = EXP2(z[r]);  // scale pre-folded in Q
        lacc += p;
#pragma unroll
        for (int r = 0; r < 4; r++) af[hh * 4 + r] = (__bf16)p[r];
      }
      // O += P @ V : A = af (in-register, pi layout), B = V[pi(key)][d]
      __builtin_amdgcn_s_setprio(1);
#pragma unroll
      for (int dt = 0; dt < 4; dt++) {
        bf16x8 bv = *(const bf16x8*)&sVt[(dt * 16 + l16) * SV_LD + kt * 32 + quad * 8];
        o[dt] = __builtin_amdgcn_mfma_f32_16x16x32_bf16(af, bv, o[dt], 0, 0, 0);
      }
      __builtin_amdgcn_s_setprio(0);
    }
  }

  // partial lsum for q=l16 within this key half: horizontal + cross-quad
  float ls = lacc[0] + lacc[1] + lacc[2] + lacc[3];
  ls += __shfl_xor(ls, 16, 64);
  ls += __shfl_xor(ls, 32, 64);

  // combine key-halves through LDS (sK reused as f32x4 scratch [dt][g*64+lane])
  __syncthreads();  // all sK/sVt reads of the main loop done
  if (quad == 0) lsbuf[wave][l16] = ls;
  f32x4* scr = (f32x4*)sK;
  if (kh == 1) {
#pragma unroll
    for (int dt = 0; dt < 4; dt++)
      scr[dt * 256 + g * 64 + lane] = o[dt];
  }
  __syncthreads();
  if (kh == 0) {
    float lst = lsbuf[g][l16] + lsbuf[4 + g][l16];
    float rls[4];
#pragma unroll
    for (int r = 0; r < 4; r++)
      rls[r] = 1.0f / __shfl(lst, quad * 4 + r, 64);  // lane q holds lsum[q]
#pragma unroll
    for (int dt = 0; dt < 4; dt++) {
      f32x4 oo = o[dt] + scr[dt * 256 + g * 64 + lane];
#pragma unroll
      for (int r = 0; r < 4; r++) {
        int s = q0 + g * 16 + quad * 4 + r;
        int d = dt * 16 + l16;
        O[base + (long)s * D_MODEL + d] = (__bf16)(oo[r] * rls[r]);
      }
    }
  }
}

extern "C" void kernel_launch(void* const* d_in, const int* in_sizes, int n_in,
                              void* d_out, int out_size, void* d_ws, size_t ws_size,
                              hipStream_t stream) {
  const float* q  = (const float*)d_in[0];
  const float* k  = (const float*)d_in[1];
  const float* v  = (const float*)d_in[2];
  const float* Wq = (const float*)d_in[3];
  const float* bq = (const float*)d_in[4];
  const float* Wk = (const float*)d_in[5];
  const float* bk = (const float*)d_in[6];
  const float* Wv = (const float*)d_in[7];
  const float* bv = (const float*)d_in[8];
  const float* Wo = (const float*)d_in[9];
  const float* bo = (const float*)d_in[10];
  float* out = (float*)d_out;

  __bf16* qc  = (__bf16*)d_ws;          // qc,kc,vc contiguous
  __bf16* Wqc = qc + 3 * ACT;           // Wq,Wk,Wv,Wo contiguous
  __bf16* wsQ = Wqc + 4 * WSZ;          // Q,K,V projections contiguous
  __bf16* wsAo = qc;                    // attn out reuses qc

  dim3 blk(256);
  // one fused cvt pass: 3*ACT + 4*WSZ = 2^24 elems, 8/thread
  cvt_all<<<dim3((3 * ACT + 4 * WSZ) / 2048), blk, 0, stream>>>(
      q, k, v, Wq, Wk, Wv, Wo, qc);

  gemm_qkv<<<dim3(D_MODEL / 128, M_ROWS / 128, 3), blk, 0, stream>>>(
      qc, Wqc, bq, bk, bv, wsQ);

  attn_kernel<<<dim3(SEQ / 64, BATCH * NUM_HEADS), dim3(512), 0, stream>>>(
      wsQ, wsQ + ACT, wsQ + 2 * ACT, wsAo);

  gemm_out<<<dim3(D_MODEL / 128, M_ROWS / 128), blk, 0, stream>>>(
      wsAo, Wqc + 3 * WSZ, bo, out);
}